// Round 6
// baseline (410.709 us; speedup 1.0000x reference)
//
#include <hip/hip_runtime.h>
#include <hip/hip_bf16.h>
#include <hip/hip_cooperative_groups.h>

namespace cg = cooperative_groups;

// GCN: 2x (GCNConv -> ReLU -> BatchNorm) -> Linear, single cooperative kernel
// (with per-phase fallback if cooperative launch is rejected).
// B=2, N=20000, E=640000, H=IN=128, OUT=10
//
// Phases:
//  0: zero cnt, S1, S2
//  1: ELL scatter (atomic cursor = degree) + GEMM1 (x fp32 -> h bf16 interleaved)
//  2: agg1 (gather, inline rsqrt norm, +bias+ReLU) + BN1 stats (shfl-reduced)
//  3: GEMM2: stage diag(a1)*W2 bf16 in LDS; d1=c1@W2; act @ W2' + d1 -> h
//  4: agg2 + BN2 stats
//  5: classifier with BN2 affine in-register
// GRID=256 (1 block/CU -> coop validation can't reject), TPB=512 (8 waves/CU).

constexpr int Nn    = 20000;
constexpr int Ee    = 640000;
constexpr int OUTd  = 10;
constexpr int Mm    = 2 * Nn;     // 40000
constexpr int ELLW  = 96;         // Poisson(32): P(deg>96) ~ 1e-14
constexpr int GRID  = 256;
constexpr int TPB   = 512;
constexpr int NT    = GRID * TPB; // 131072
constexpr int NTILE = Mm / 64;    // 625
#define EPSV 1e-5f

using frag16 = __attribute__((ext_vector_type(8))) short;  // 8 bf16
using f32x4  = __attribute__((ext_vector_type(4))) float;

__device__ inline short bf(float f) {
    union { __hip_bfloat16 h; short s; } u;
    u.h = __float2bfloat16(f);
    return u.s;
}
__device__ inline float lo16(unsigned u) { union { unsigned v; float f; } x; x.v = u << 16;        return x.f; }
__device__ inline float hi16(unsigned u) { union { unsigned v; float f; } x; x.v = u & 0xffff0000u; return x.f; }
__device__ inline unsigned pack2(float f0, float f1) {
    return (unsigned)(unsigned short)bf(f0) | ((unsigned)(unsigned short)bf(f1) << 16);
}
__device__ inline void accum8(const uint4& v, float w, float* acc) {
    acc[0] += w * lo16(v.x); acc[1] += w * hi16(v.x);
    acc[2] += w * lo16(v.y); acc[3] += w * hi16(v.y);
    acc[4] += w * lo16(v.z); acc[5] += w * hi16(v.z);
    acc[6] += w * lo16(v.w); acc[7] += w * hi16(v.w);
}

__global__ __launch_bounds__(TPB, 2) void mega_k(
    const float* __restrict__ x,
    const float* __restrict__ W1, const float* __restrict__ b1,
    const float* __restrict__ W2, const float* __restrict__ b2,
    const float* __restrict__ g1, const float* __restrict__ bt1,
    const float* __restrict__ g2, const float* __restrict__ bt2,
    const float* __restrict__ Wc, const float* __restrict__ bc,
    const int* __restrict__ srcp, const int* __restrict__ dstp,
    unsigned short* __restrict__ h, unsigned short* __restrict__ act,
    int* __restrict__ cnt, int* __restrict__ ell,
    float* __restrict__ S1, float* __restrict__ S2,
    float* __restrict__ out,
    int ph_lo, int ph_hi, int do_sync)
{
    cg::grid_group gg = cg::this_grid();
    __shared__ alignas(16) short Wl[128 * 136];  // 34816 B; stride 272B -> free 2-way
    __shared__ float aux[2048];                  // 8 KB: wave partials / affine / d

    const int t    = threadIdx.x;
    const int gtid = blockIdx.x * TPB + t;
    const int wv = t >> 6, l64 = t & 63;
    const int row_q = l64 >> 4, lane16 = l64 & 15;
    const int grp4 = wv >> 2;            // 4-wave GEMM group 0/1
    const int wg   = wv & 3;             // wave-in-group

    // ---------------- Ph0: zero cnt + stats ----------------
    if (ph_lo <= 0) {
        for (int i = gtid; i < Nn; i += NT) cnt[i] = 0;
        if (gtid < 256) { S1[gtid] = 0.f; S2[gtid] = 0.f; }
    }
    if (do_sync) gg.sync();

    // ---------------- Ph1: ELL scatter + GEMM1 ----------------
    if (ph_lo <= 1 && ph_hi >= 1) {
        for (int e = gtid; e < Ee; e += NT) {
            int d = dstp[e];
            int pos = atomicAdd(&cnt[d], 1);
            if (pos < ELLW) ell[(size_t)d * ELLW + pos] = srcp[e];
        }
        for (int it = 0; it < 4; ++it) {
            int lin = it * TPB + t;       // 0..2047
            int kp  = lin & 63;
            int n4  = (lin >> 6) * 4;
            float4 w0 = *(const float4*)(W1 + (size_t)(2 * kp) * 128 + n4);
            float4 w1 = *(const float4*)(W1 + (size_t)(2 * kp + 1) * 128 + n4);
            *(unsigned*)&Wl[(n4 + 0) * 136 + 2 * kp] = pack2(w0.x, w1.x);
            *(unsigned*)&Wl[(n4 + 1) * 136 + 2 * kp] = pack2(w0.y, w1.y);
            *(unsigned*)&Wl[(n4 + 2) * 136 + 2 * kp] = pack2(w0.z, w1.z);
            *(unsigned*)&Wl[(n4 + 3) * 136 + 2 * kp] = pack2(w0.w, w1.w);
        }
        __syncthreads();
        for (int tile = blockIdx.x * 2 + grp4; tile < NTILE; tile += GRID * 2) {
            int row0 = tile * 64 + wg * 16;
            const float* Arow = x + (size_t)(row0 + lane16) * 128;
            frag16 a[4];
            #pragma unroll
            for (int q = 0; q < 4; ++q) {
                int k0 = q * 32 + row_q * 8;
                float4 v0 = *(const float4*)(Arow + k0);
                float4 v1 = *(const float4*)(Arow + k0 + 4);
                frag16 fa = { bf(v0.x), bf(v0.y), bf(v0.z), bf(v0.w),
                              bf(v1.x), bf(v1.y), bf(v1.z), bf(v1.w) };
                a[q] = fa;
            }
            f32x4 acc[8];
            #pragma unroll
            for (int c = 0; c < 8; ++c) acc[c] = (f32x4){0.f, 0.f, 0.f, 0.f};
            #pragma unroll
            for (int c = 0; c < 8; ++c) {
                int n = c * 16 + lane16;
                #pragma unroll
                for (int q = 0; q < 4; ++q) {
                    frag16 b = *(const frag16*)&Wl[n * 136 + q * 32 + row_q * 8];
                    acc[c] = __builtin_amdgcn_mfma_f32_16x16x32_bf16(a[q], b, acc[c], 0, 0, 0);
                }
            }
            #pragma unroll
            for (int r = 0; r < 4; ++r) {
                int rg = row0 + row_q * 4 + r;
                int b  = rg >= Nn;
                int n  = rg - b * Nn;
                unsigned short* dstw = h + (size_t)n * 256 + b * 128;
                #pragma unroll
                for (int c = 0; c < 8; ++c)
                    dstw[c * 16 + lane16] = (unsigned short)bf(acc[c][r]);
            }
        }
    }
    if (do_sync) gg.sync();

    // ---------------- agg + stats lambda ----------------
    auto agg_phase = [&](const unsigned short* __restrict__ hin,
                         const float* __restrict__ bias,
                         unsigned short* __restrict__ aout,
                         float* __restrict__ S) {
        const uint4* h4 = (const uint4*)hin;
        const int l  = t & 31;
        const int cb = (l & 15) * 8;
        const int bsel = l >> 4;
        float s8[8], q8[8];
        #pragma unroll
        for (int j = 0; j < 8; ++j) { s8[j] = 0.f; q8[j] = 0.f; }

        float4 bb0 = *(const float4*)(bias + cb);
        float4 bb1 = *(const float4*)(bias + cb + 4);

        for (int grp = blockIdx.x; grp < Nn / 16; grp += GRID) {
            int n = grp * 16 + (t >> 5);
            int deg = cnt[n];
            float dn = rsqrtf((float)deg + 1.0f);
            float sl = dn * dn;
            if (deg > ELLW) deg = ELLW;
            const int* row = ell + (size_t)n * ELLW;

            uint4 u = h4[(size_t)n * 32 + l];
            float acc[8];
            acc[0] = sl * lo16(u.x); acc[1] = sl * hi16(u.x);
            acc[2] = sl * lo16(u.y); acc[3] = sl * hi16(u.y);
            acc[4] = sl * lo16(u.z); acc[5] = sl * hi16(u.z);
            acc[6] = sl * lo16(u.w); acc[7] = sl * hi16(u.w);

            int j = 0;
            for (; j + 7 < deg; j += 8) {
                int s0 = row[j], s1 = row[j+1], s2 = row[j+2], s3 = row[j+3];
                int s4 = row[j+4], s5 = row[j+5], s6 = row[j+6], s7 = row[j+7];
                float w0 = rsqrtf((float)cnt[s0] + 1.f) * dn;
                float w1 = rsqrtf((float)cnt[s1] + 1.f) * dn;
                float w2 = rsqrtf((float)cnt[s2] + 1.f) * dn;
                float w3 = rsqrtf((float)cnt[s3] + 1.f) * dn;
                float w4 = rsqrtf((float)cnt[s4] + 1.f) * dn;
                float w5 = rsqrtf((float)cnt[s5] + 1.f) * dn;
                float w6 = rsqrtf((float)cnt[s6] + 1.f) * dn;
                float w7 = rsqrtf((float)cnt[s7] + 1.f) * dn;
                uint4 v0 = h4[(size_t)s0 * 32 + l];
                uint4 v1 = h4[(size_t)s1 * 32 + l];
                uint4 v2 = h4[(size_t)s2 * 32 + l];
                uint4 v3 = h4[(size_t)s3 * 32 + l];
                uint4 v4 = h4[(size_t)s4 * 32 + l];
                uint4 v5 = h4[(size_t)s5 * 32 + l];
                uint4 v6 = h4[(size_t)s6 * 32 + l];
                uint4 v7 = h4[(size_t)s7 * 32 + l];
                accum8(v0, w0, acc); accum8(v1, w1, acc); accum8(v2, w2, acc); accum8(v3, w3, acc);
                accum8(v4, w4, acc); accum8(v5, w5, acc); accum8(v6, w6, acc); accum8(v7, w7, acc);
            }
            for (; j + 3 < deg; j += 4) {
                int s0 = row[j], s1 = row[j+1], s2 = row[j+2], s3 = row[j+3];
                float w0 = rsqrtf((float)cnt[s0] + 1.f) * dn;
                float w1 = rsqrtf((float)cnt[s1] + 1.f) * dn;
                float w2 = rsqrtf((float)cnt[s2] + 1.f) * dn;
                float w3 = rsqrtf((float)cnt[s3] + 1.f) * dn;
                uint4 v0 = h4[(size_t)s0 * 32 + l];
                uint4 v1 = h4[(size_t)s1 * 32 + l];
                uint4 v2 = h4[(size_t)s2 * 32 + l];
                uint4 v3 = h4[(size_t)s3 * 32 + l];
                accum8(v0, w0, acc); accum8(v1, w1, acc); accum8(v2, w2, acc); accum8(v3, w3, acc);
            }
            for (; j < deg; ++j) {
                int s0 = row[j];
                float w0 = rsqrtf((float)cnt[s0] + 1.f) * dn;
                uint4 v0 = h4[(size_t)s0 * 32 + l];
                accum8(v0, w0, acc);
            }

            float o0 = fmaxf(acc[0] + bb0.x, 0.f), o1 = fmaxf(acc[1] + bb0.y, 0.f);
            float o2 = fmaxf(acc[2] + bb0.z, 0.f), o3 = fmaxf(acc[3] + bb0.w, 0.f);
            float o4 = fmaxf(acc[4] + bb1.x, 0.f), o5 = fmaxf(acc[5] + bb1.y, 0.f);
            float o6 = fmaxf(acc[6] + bb1.z, 0.f), o7 = fmaxf(acc[7] + bb1.w, 0.f);

            uint4 st;
            st.x = pack2(o0, o1); st.y = pack2(o2, o3); st.z = pack2(o4, o5); st.w = pack2(o6, o7);
            *(uint4*)(aout + (size_t)n * 256 + bsel * 128 + cb) = st;

            s8[0] += o0; q8[0] += o0 * o0;  s8[1] += o1; q8[1] += o1 * o1;
            s8[2] += o2; q8[2] += o2 * o2;  s8[3] += o3; q8[3] += o3 * o3;
            s8[4] += o4; q8[4] += o4 * o4;  s8[5] += o5; q8[5] += o5 * o5;
            s8[6] += o6; q8[6] += o6 * o6;  s8[7] += o7; q8[7] += o7 * o7;
        }

        // reduce lanes {l, l^16, l^32, l^48} (same cols, both batches/nodes)
        #pragma unroll
        for (int j = 0; j < 8; ++j) {
            s8[j] += __shfl_xor(s8[j], 16, 64); s8[j] += __shfl_xor(s8[j], 32, 64);
            q8[j] += __shfl_xor(q8[j], 16, 64); q8[j] += __shfl_xor(q8[j], 32, 64);
        }
        if (l64 < 16) {
            #pragma unroll
            for (int j = 0; j < 8; ++j) {
                aux[wv * 256 + l64 * 8 + j]       = s8[j];
                aux[wv * 256 + 128 + l64 * 8 + j] = q8[j];
            }
        }
        __syncthreads();
        if (t < 128) {
            float s = 0.f, qq = 0.f;
            #pragma unroll
            for (int w = 0; w < 8; ++w) { s += aux[w * 256 + t]; qq += aux[w * 256 + 128 + t]; }
            atomicAdd(&S[t], s);
            atomicAdd(&S[128 + t], qq);
        }
        __syncthreads();
    };

    // ---------------- Ph2: agg1 + stats -> S1 ----------------
    if (ph_lo <= 2 && ph_hi >= 2) agg_phase(h, b1, act, S1);
    if (do_sync) gg.sync();

    // ---------------- Ph3: GEMM2 (BN1 folded) ----------------
    if (ph_lo <= 3 && ph_hi >= 3) {
        if (t < 128) {
            const float invM = 1.0f / (float)Mm;
            float m   = S1[t] * invM;
            float var = S1[128 + t] * invM - m * m;
            float a   = g1[t] * rsqrtf(var + EPSV);
            aux[t]       = a;
            aux[128 + t] = bt1[t] - m * a;
        }
        __syncthreads();
        for (int it = 0; it < 4; ++it) {
            int lin = it * TPB + t;
            int kp  = lin & 63;
            int n4  = (lin >> 6) * 4;
            float a0 = aux[2 * kp], a1 = aux[2 * kp + 1];
            float4 w0 = *(const float4*)(W2 + (size_t)(2 * kp) * 128 + n4);
            float4 w1 = *(const float4*)(W2 + (size_t)(2 * kp + 1) * 128 + n4);
            w0.x *= a0; w0.y *= a0; w0.z *= a0; w0.w *= a0;
            w1.x *= a1; w1.y *= a1; w1.z *= a1; w1.w *= a1;
            *(unsigned*)&Wl[(n4 + 0) * 136 + 2 * kp] = pack2(w0.x, w1.x);
            *(unsigned*)&Wl[(n4 + 1) * 136 + 2 * kp] = pack2(w0.y, w1.y);
            *(unsigned*)&Wl[(n4 + 2) * 136 + 2 * kp] = pack2(w0.z, w1.z);
            *(unsigned*)&Wl[(n4 + 3) * 136 + 2 * kp] = pack2(w0.w, w1.w);
        }
        if (t < 128) {
            float d = 0.f;
            for (int k = 0; k < 128; ++k) d += aux[128 + k] * W2[(size_t)k * 128 + t];
            aux[256 + t] = d;
        }
        __syncthreads();

        for (int tile = blockIdx.x * 2 + grp4; tile < NTILE; tile += GRID * 2) {
            int row0 = tile * 64 + wg * 16;
            int rgA = row0 + lane16;
            int bA  = rgA >= Nn;
            int nA  = rgA - bA * Nn;
            const unsigned short* Arow = act + (size_t)nA * 256 + bA * 128;
            frag16 a[4];
            #pragma unroll
            for (int q = 0; q < 4; ++q)
                a[q] = *(const frag16*)(Arow + q * 32 + row_q * 8);

            f32x4 acc[8];
            #pragma unroll
            for (int c = 0; c < 8; ++c) {
                float d = aux[256 + c * 16 + lane16];
                acc[c] = (f32x4){d, d, d, d};
            }
            #pragma unroll
            for (int c = 0; c < 8; ++c) {
                int n = c * 16 + lane16;
                #pragma unroll
                for (int q = 0; q < 4; ++q) {
                    frag16 b = *(const frag16*)&Wl[n * 136 + q * 32 + row_q * 8];
                    acc[c] = __builtin_amdgcn_mfma_f32_16x16x32_bf16(a[q], b, acc[c], 0, 0, 0);
                }
            }
            #pragma unroll
            for (int r = 0; r < 4; ++r) {
                int rg = row0 + row_q * 4 + r;
                int b  = rg >= Nn;
                int n  = rg - b * Nn;
                unsigned short* dstw = h + (size_t)n * 256 + b * 128;
                #pragma unroll
                for (int c = 0; c < 8; ++c)
                    dstw[c * 16 + lane16] = (unsigned short)bf(acc[c][r]);
            }
        }
    }
    if (do_sync) gg.sync();

    // ---------------- Ph4: agg2 + stats -> S2 ----------------
    if (ph_lo <= 4 && ph_hi >= 4) agg_phase(h, b2, act, S2);
    if (do_sync) gg.sync();

    // ---------------- Ph5: classifier (BN2 affine in-register) ----------------
    if (ph_hi >= 5) {
        float* Wlf = (float*)Wl;  // 1280 floats
        if (t < 128) {
            const float invM = 1.0f / (float)Mm;
            float m   = S2[t] * invM;
            float var = S2[128 + t] * invM - m * m;
            float a   = g2[t] * rsqrtf(var + EPSV);
            aux[t]       = a;
            aux[128 + t] = bt2[t] - m * a;
        }
        for (int i = t; i < 128 * OUTd; i += TPB) Wlf[i] = Wc[i];
        if (t < OUTd) aux[256 + t] = bc[t];
        __syncthreads();

        for (int r = gtid; r < Mm; r += NT) {
            int b = r >= Nn;
            int n = r - b * Nn;
            float accv[OUTd];
            #pragma unroll
            for (int jj = 0; jj < OUTd; jj++) accv[jj] = 0.f;
            const uint4* a4 = (const uint4*)(act + (size_t)n * 256 + b * 128);
            #pragma unroll 4
            for (int k4 = 0; k4 < 16; k4++) {
                uint4 u = a4[k4];
                int k = k4 * 8;
                float e0 = lo16(u.x) * aux[k+0] + aux[128+k+0];
                float e1 = hi16(u.x) * aux[k+1] + aux[128+k+1];
                float e2 = lo16(u.y) * aux[k+2] + aux[128+k+2];
                float e3 = hi16(u.y) * aux[k+3] + aux[128+k+3];
                float e4 = lo16(u.z) * aux[k+4] + aux[128+k+4];
                float e5 = hi16(u.z) * aux[k+5] + aux[128+k+5];
                float e6 = lo16(u.w) * aux[k+6] + aux[128+k+6];
                float e7 = hi16(u.w) * aux[k+7] + aux[128+k+7];
                #pragma unroll
                for (int jj = 0; jj < OUTd; jj++) {
                    accv[jj] += e0 * Wlf[(k+0) * OUTd + jj];
                    accv[jj] += e1 * Wlf[(k+1) * OUTd + jj];
                    accv[jj] += e2 * Wlf[(k+2) * OUTd + jj];
                    accv[jj] += e3 * Wlf[(k+3) * OUTd + jj];
                    accv[jj] += e4 * Wlf[(k+4) * OUTd + jj];
                    accv[jj] += e5 * Wlf[(k+5) * OUTd + jj];
                    accv[jj] += e6 * Wlf[(k+6) * OUTd + jj];
                    accv[jj] += e7 * Wlf[(k+7) * OUTd + jj];
                }
            }
            #pragma unroll
            for (int jj = 0; jj < OUTd; jj++) out[(size_t)r * OUTd + jj] = accv[jj] + aux[256 + jj];
        }
    }
}

extern "C" void kernel_launch(void* const* d_in, const int* in_sizes, int n_in,
                              void* d_out, int out_size, void* d_ws, size_t ws_size,
                              hipStream_t stream) {
    (void)in_sizes; (void)n_in; (void)out_size; (void)ws_size;

    const float* x   = (const float*)d_in[0];
    const float* W1  = (const float*)d_in[1];
    const float* b1  = (const float*)d_in[2];
    const float* W2  = (const float*)d_in[3];
    const float* b2  = (const float*)d_in[4];
    const float* g1  = (const float*)d_in[5];
    const float* bt1 = (const float*)d_in[6];
    const float* g2  = (const float*)d_in[7];
    const float* bt2 = (const float*)d_in[8];
    const float* Wc  = (const float*)d_in[9];
    const float* bc  = (const float*)d_in[10];
    const int*   ei  = (const int*)d_in[11];
    const int* srcp = ei;        // edge_index[0]
    const int* dstp = ei + Ee;   // edge_index[1]

    char* ws = (char*)d_ws;
    size_t off = 0;
    auto alloc = [&](size_t bytes) -> void* {
        void* p = ws + off;
        off += (bytes + 511) & ~(size_t)511;
        return p;
    };
    unsigned short* h   = (unsigned short*)alloc((size_t)Mm * 128 * 2);
    unsigned short* act = (unsigned short*)alloc((size_t)Mm * 128 * 2);
    int*   cnt = (int*)alloc(Nn * 4);
    int*   ell = (int*)alloc((size_t)Nn * ELLW * 4);
    float* S1  = (float*)alloc(256 * 4);
    float* S2  = (float*)alloc(256 * 4);
    float* out = (float*)d_out;

    int ph_lo = 0, ph_hi = 5, dosync = 1;
    void* args[] = { &x, &W1, &b1, &W2, &b2, &g1, &bt1, &g2, &bt2, &Wc, &bc,
                     &srcp, &dstp, &h, &act, &cnt, &ell, &S1, &S2, &out,
                     &ph_lo, &ph_hi, &dosync };
    hipError_t err = hipLaunchCooperativeKernel((void*)mega_k, dim3(GRID), dim3(TPB),
                                                args, 0, stream);
    if (err != hipSuccess) {
        // fallback: one launch per phase, kernel boundaries provide the sync
        for (int p = 0; p < 6; ++p) {
            mega_k<<<GRID, TPB, 0, stream>>>(x, W1, b1, W2, b2, g1, bt1, g2, bt2,
                                             Wc, bc, srcp, dstp, h, act, cnt, ell,
                                             S1, S2, out, p, p, 0);
        }
    }
}